// Round 20
// baseline (238.462 us; speedup 1.0000x reference)
//
#include <hip/hip_runtime.h>
#include <hip/hip_bf16.h>
#include <type_traits>

// EncoderBlock on MI355X — bf16 MFMA everywhere.
// R20: attn was TLP-starved (512 blocks = 2/CU, Occ 18%). kv-split x2:
// m==0 softmax is a pure sum, so halves merge exactly o=(o0+o1)/(l0+l1).
// Grid 16x32x2 = 1024 blocks (16 waves/CU). Partial O^T (f32) -> F1 region
// (dead until FFN1); partial l -> H2 region (dead until LN2); combine kernel
// produces ao. attn sync reverted to __syncthreads (R19's T4 was negative).
// Everything else identical to R18 (225.4us).

typedef __attribute__((ext_vector_type(8))) short short8v;
typedef __attribute__((ext_vector_type(4))) float f32x4;
typedef __attribute__((ext_vector_type(4))) unsigned uint4v;

#define D_MODEL 1024
#define SEQ 2048
#define NROWS 4096   // B*S

__device__ __forceinline__ short f2bs(float f) {
  __hip_bfloat16 h = __float2bfloat16(f);
  return __builtin_bit_cast(short, h);
}

__device__ __forceinline__ unsigned cvtpk(float lo, float hi) {
  unsigned r;
  asm("v_cvt_pk_bf16_f32 %0, %1, %2" : "=v"(r) : "v"(lo), "v"(hi));
  return r;
}

__device__ __forceinline__ void perm16swap(unsigned& a, unsigned& b) {
  asm volatile("v_permlane16_swap_b32 %0, %1" : "+v"(a), "+v"(b));
}

__device__ __forceinline__ void async_copy16(const void* g, void* l) {
  __builtin_amdgcn_global_load_lds(
      (__attribute__((address_space(1))) void*)g,
      (__attribute__((address_space(3))) void*)l,
      16, 0, 0);
}

// ---------------- weight transpose + fp32->bf16 convert (+scale) -------------
__global__ __launch_bounds__(256)
void transpose4_bf16_kernel(const float* __restrict__ wq, const float* __restrict__ wk,
                            const float* __restrict__ wv, const float* __restrict__ wo,
                            short* __restrict__ oq, short* __restrict__ ow,
                            float qscale) {
  __shared__ float tile[32][33];
  const int z = blockIdx.z;
  const float* in = (z == 0) ? wq : (z == 1) ? wk : (z == 2) ? wv : wo;
  short* out = (z < 3) ? (oq + (size_t)z * 1024 * 1024) : ow;
  const float scale = (z == 0) ? qscale : 1.0f;
  const int n0 = blockIdx.x * 32, k0 = blockIdx.y * 32;
  const int tx = threadIdx.x, ty = threadIdx.y;  // (32,8)
#pragma unroll
  for (int j = 0; j < 4; ++j)
    tile[ty + j * 8][tx] = in[(size_t)(k0 + ty + j * 8) * 1024 + n0 + tx];
  __syncthreads();
#pragma unroll
  for (int j = 0; j < 4; ++j)
    out[(size_t)(n0 + ty + j * 8) * 1024 + k0 + tx] = f2bs(tile[tx][ty + j * 8] * scale);
}

// w1 (1024x4096) and w2 (4096x1024) in one launch (z swaps grid roles).
__global__ __launch_bounds__(256)
void transpose_ffn_kernel(const float* __restrict__ w1, const float* __restrict__ w2,
                          short* __restrict__ o1, short* __restrict__ o2) {
  __shared__ float tile[32][33];
  const int z = blockIdx.z;
  const float* in = z ? w2 : w1;
  short* out = z ? o2 : o1;
  const int K = z ? 4096 : 1024, N = z ? 1024 : 4096;
  const int n0 = (z ? blockIdx.y : blockIdx.x) * 32;
  const int k0 = (z ? blockIdx.x : blockIdx.y) * 32;
  const int tx = threadIdx.x, ty = threadIdx.y;  // (32,8)
#pragma unroll
  for (int j = 0; j < 4; ++j)
    tile[ty + j * 8][tx] = in[(size_t)(k0 + ty + j * 8) * N + n0 + tx];
  __syncthreads();
#pragma unroll
  for (int j = 0; j < 4; ++j)
    out[(size_t)(n0 + ty + j * 8) * K + k0 + tx] = f2bs(tile[tx][ty + j * 8]);
}

// v-part of qkv (token, 2048 + h*64 + d) -> vt[(b*16+h)*64 + d][kv=s]
__global__ __launch_bounds__(256)
void transpose_v_kernel(const short* __restrict__ qkv, short* __restrict__ vt) {
  __shared__ short tile[32][36];
  const int bh = blockIdx.z, b = bh >> 4, h = bh & 15;
  const int s0 = blockIdx.x * 32, d0 = blockIdx.y * 32;
  const int tid = threadIdx.x;
  const short* src = qkv + ((size_t)b * SEQ) * 3072 + 2048 + h * 64;
  const int row = tid >> 3, c4 = (tid & 7) * 4;
  *(short4*)&tile[row][c4] = *(const short4*)&src[(size_t)(s0 + row) * 3072 + d0 + c4];
  __syncthreads();
  short* dst = vt + (size_t)bh * 64 * SEQ;
  const int dr = tid >> 5, sc = tid & 31;
#pragma unroll
  for (int j = 0; j < 4; ++j)
    dst[(size_t)(d0 + dr + j * 8) * SEQ + s0 + sc] = tile[sc][dr + j * 8];
}

__global__ void concat_bias_kernel(const float* __restrict__ bq, const float* __restrict__ bk,
                                   const float* __restrict__ bv, float* __restrict__ outb,
                                   float qscale) {
  int i = blockIdx.x * 256 + threadIdx.x;  // 3072 total
  float v = (i < 1024) ? bq[i] * qscale : (i < 2048 ? bk[i - 1024] : bv[i - 2048]);
  outb[i] = v;
}

// ---------------- LayerNorm (torch semantics: ddof=1, eps on std) -> bf16 ----
__global__ __launch_bounds__(256)
void layernorm_kernel(const float* __restrict__ x, short* __restrict__ out,
                      const float* __restrict__ alpha, const float* __restrict__ beta) {
  const int row = blockIdx.x;
  const int t = threadIdx.x;
  float4 v = ((const float4*)(x + (size_t)row * D_MODEL))[t];
  float s = v.x + v.y + v.z + v.w;
  float sq = v.x * v.x + v.y * v.y + v.z * v.z + v.w * v.w;
#pragma unroll
  for (int m = 1; m < 64; m <<= 1) {
    s += __shfl_xor(s, m, 64);
    sq += __shfl_xor(sq, m, 64);
  }
  __shared__ float sh_s[4], sh_q[4];
  const int wid = t >> 6;
  if ((t & 63) == 0) { sh_s[wid] = s; sh_q[wid] = sq; }
  __syncthreads();
  s = sh_s[0] + sh_s[1] + sh_s[2] + sh_s[3];
  sq = sh_q[0] + sh_q[1] + sh_q[2] + sh_q[3];
  const float mean = s * (1.0f / 1024.0f);
  const float var = fmaxf(0.0f, (sq - 1024.0f * mean * mean) * (1.0f / 1023.0f));
  const float scl = alpha[0] / (sqrtf(var) + 1e-6f);
  const float sft = beta[0];
  short4 o;
  o.x = f2bs((v.x - mean) * scl + sft);
  o.y = f2bs((v.y - mean) * scl + sft);
  o.z = f2bs((v.z - mean) * scl + sft);
  o.w = f2bs((v.w - mean) * scl + sft);
  ((short4*)(out + (size_t)row * D_MODEL))[t] = o;
}

// ---------------- big GEMM: 128x128, BK=64, single-buffer, full swizzle ------
template <int MF, int NF, bool RELU, bool RESID, bool OUT_BF16>
__global__ __launch_bounds__(256)
void gemm_bt_sb_kernel(const short* __restrict__ A, const short* __restrict__ Bt,
                       const float* __restrict__ bias, const float* __restrict__ resid,
                       void* __restrict__ out, int M, int N, int K) {
  constexpr int BM = MF * 32, BN = NF * 32, BK = 64;
  __shared__ short As[BM * BK];
  __shared__ short Bs[BN * BK];
  const int tid = threadIdx.x;
  const int lane = tid & 63, wid = tid >> 6;
  const int wr = wid >> 1, wc = wid & 1;
  const int l15 = lane & 15, kg = lane >> 4;

  const int gx = gridDim.x;
  const int nwg = gx * gridDim.y;
  const int bid = blockIdx.y * gx + blockIdx.x;
  const int tilei = (bid & 7) * (nwg >> 3) + (bid >> 3);
  const int m0 = (tilei / gx) * BM, n0 = (tilei % gx) * BN;

  f32x4 acc[MF][NF];
#pragma unroll
  for (int m = 0; m < MF; ++m)
#pragma unroll
    for (int n = 0; n < NF; ++n) acc[m][n] = (f32x4){0.f, 0.f, 0.f, 0.f};

  const int r0 = tid >> 3, c0 = tid & 7;
  const int csw = (c0 ^ (r0 & 7)) << 3;
  const short* pa = A + (size_t)(m0 + r0) * K + csw;
  const short* pb = Bt + (size_t)(n0 + r0) * K + csw;

  const int NT = K / BK;
  for (int t = 0; t < NT; ++t) {
    const size_t ko = (size_t)t * BK;
#pragma unroll
    for (int it = 0; it < MF; ++it)
      async_copy16(pa + (size_t)it * 32 * K + ko, &As[(tid + it * 256) * 8]);
#pragma unroll
    for (int it = 0; it < NF; ++it)
      async_copy16(pb + (size_t)it * 32 * K + ko, &Bs[(tid + it * 256) * 8]);
    __syncthreads();

    short8v a[2][MF], b[2][NF];
#pragma unroll
    for (int m = 0; m < MF; ++m) {
      const int row = wr * MF * 16 + m * 16 + l15;
#pragma unroll
      for (int kt = 0; kt < 2; ++kt)
        a[kt][m] = *(const short8v*)&As[row * BK + (((kg + 4 * kt) ^ (row & 7)) << 3)];
    }
#pragma unroll
    for (int n = 0; n < NF; ++n) {
      const int row = wc * NF * 16 + n * 16 + l15;
#pragma unroll
      for (int kt = 0; kt < 2; ++kt)
        b[kt][n] = *(const short8v*)&Bs[row * BK + (((kg + 4 * kt) ^ (row & 7)) << 3)];
    }
    __builtin_amdgcn_s_setprio(1);
#pragma unroll
    for (int kt = 0; kt < 2; ++kt)
#pragma unroll
      for (int m = 0; m < MF; ++m)
#pragma unroll
        for (int n = 0; n < NF; ++n)
          acc[m][n] = __builtin_amdgcn_mfma_f32_16x16x32_bf16(a[kt][m], b[kt][n], acc[m][n], 0, 0, 0);
    __builtin_amdgcn_s_setprio(0);
    __syncthreads();
  }

#pragma unroll
  for (int m = 0; m < MF; ++m) {
#pragma unroll
    for (int n = 0; n < NF; ++n) {
      const int col = n0 + wc * NF * 16 + n * 16 + l15;
      const float bv = bias[col];
#pragma unroll
      for (int r = 0; r < 4; ++r) {
        const size_t row = (size_t)(m0 + wr * MF * 16 + m * 16 + kg * 4 + r);
        float v = acc[m][n][r] + bv;
        if (RELU) v = fmaxf(v, 0.0f);
        if (RESID) v += resid[row * N + col];
        if (OUT_BF16)
          ((short*)out)[row * N + col] = f2bs(v);
        else
          ((float*)out)[row * N + col] = v;
      }
    }
  }
}

// ---------------- skinny GEMM: 64x64, BK=64, dbuf, hoisted staging (R15) -----
template <bool RELU, bool RESID, bool OUT_BF16>
__global__ __launch_bounds__(256)
void gemm_bt_k64_kernel(const short* __restrict__ A, const short* __restrict__ Bt,
                        const float* __restrict__ bias, const float* __restrict__ resid,
                        void* __restrict__ out, int M, int N, int K) {
  constexpr int BM = 64, BN = 64, BK = 64;
  __shared__ short As[2][BM * BK];
  __shared__ short Bs[2][BN * BK];
  const int tid = threadIdx.x;
  const int lane = tid & 63, wid = tid >> 6;
  const int wr = wid >> 1, wc = wid & 1;
  const int l15 = lane & 15, kg = lane >> 4;

  const int gx = gridDim.x;
  const int nwg = gx * gridDim.y;
  const int bid = blockIdx.y * gx + blockIdx.x;
  const int tilei = (bid & 7) * (nwg >> 3) + (bid >> 3);
  const int m0 = (tilei / gx) * BM, n0 = (tilei % gx) * BN;

  f32x4 acc[2][2];
#pragma unroll
  for (int m = 0; m < 2; ++m)
#pragma unroll
    for (int n = 0; n < 2; ++n) acc[m][n] = (f32x4){0.f, 0.f, 0.f, 0.f};

  const int rA0 = tid >> 3, cA0 = (((tid & 7)) ^ (rA0 & 7)) << 3;
  const int rA1 = (tid + 256) >> 3, cA1 = (((tid + 256) & 7) ^ (rA1 & 7)) << 3;
  const short* pa0 = A + (size_t)(m0 + rA0) * K + cA0;
  const short* pa1 = A + (size_t)(m0 + rA1) * K + cA1;
  const short* pb0 = Bt + (size_t)(n0 + rA0) * K + cA0;
  const short* pb1 = Bt + (size_t)(n0 + rA1) * K + cA1;

  auto stage = [&](int buf, int t) {
    const size_t ko = (size_t)t * BK;
    async_copy16(pa0 + ko, &As[buf][tid * 8]);
    async_copy16(pa1 + ko, &As[buf][(tid + 256) * 8]);
    async_copy16(pb0 + ko, &Bs[buf][tid * 8]);
    async_copy16(pb1 + ko, &Bs[buf][(tid + 256) * 8]);
  };

  const int NT = K / BK;

  auto bodyk = [&](auto BUFC, int t) {
    constexpr int buf = decltype(BUFC)::value;
    if (t + 1 < NT) stage(buf ^ 1, t + 1);
    short8v a[2][2], b[2][2];
#pragma unroll
    for (int m = 0; m < 2; ++m) {
      const int row = wr * 32 + m * 16 + l15;
#pragma unroll
      for (int kt = 0; kt < 2; ++kt)
        a[kt][m] = *(const short8v*)&As[buf][row * BK + (((kg + 4 * kt) ^ (row & 7)) << 3)];
    }
#pragma unroll
    for (int n = 0; n < 2; ++n) {
      const int row = wc * 32 + n * 16 + l15;
#pragma unroll
      for (int kt = 0; kt < 2; ++kt)
        b[kt][n] = *(const short8v*)&Bs[buf][row * BK + (((kg + 4 * kt) ^ (row & 7)) << 3)];
    }
    __builtin_amdgcn_s_setprio(1);
#pragma unroll
    for (int kt = 0; kt < 2; ++kt)
#pragma unroll
      for (int m = 0; m < 2; ++m)
#pragma unroll
        for (int n = 0; n < 2; ++n)
          acc[m][n] = __builtin_amdgcn_mfma_f32_16x16x32_bf16(a[kt][m], b[kt][n], acc[m][n], 0, 0, 0);
    __builtin_amdgcn_s_setprio(0);
    __syncthreads();
  };

  stage(0, 0);
  __syncthreads();
  for (int t = 0; t < NT; t += 2) {
    bodyk(std::integral_constant<int, 0>{}, t);
    bodyk(std::integral_constant<int, 1>{}, t + 1);
  }

#pragma unroll
  for (int m = 0; m < 2; ++m) {
#pragma unroll
    for (int n = 0; n < 2; ++n) {
      const int col = n0 + wc * 32 + n * 16 + l15;
      const float bv = bias[col];
#pragma unroll
      for (int r = 0; r < 4; ++r) {
        const size_t row = (size_t)(m0 + wr * 32 + m * 16 + kg * 4 + r);
        float v = acc[m][n][r] + bv;
        if (RELU) v = fmaxf(v, 0.0f);
        if (RESID) v += resid[row * N + col];
        if (OUT_BF16)
          ((short*)out)[row * N + col] = f2bs(v);
        else
          ((float*)out)[row * N + col] = v;
      }
    }
  }
}

// ---------------- Flash attention: QBLK=128, kv-split x2 (R20) ---------------
// blockIdx.z = kv half. Writes f32 partial O^T and partial l (m==0 softmax:
// halves merge exactly by summation). Sync = __syncthreads (R18 proven).
__global__ __launch_bounds__(256)
void attn_kernel(const short* __restrict__ qkv, const short* __restrict__ vt,
                 float* __restrict__ po, float* __restrict__ lp) {
  const int bh = blockIdx.y;        // b*16+h
  const int b = bh >> 4, h = bh & 15;
  const int q0 = blockIdx.x * 128;
  const int half = blockIdx.z;
  const int kvbase = half * (SEQ / 2);
  const int tid = threadIdx.x;
  const int lane = tid & 63, wid = tid >> 6;
  const int l15 = lane & 15, kg = lane >> 4;

  __shared__ short Ks[2][64 * 64];
  __shared__ short Vs[2][64 * 64];

  const size_t RS = 3072;
  const short* Qb = qkv + (size_t)b * SEQ * RS + h * 64;
  const short* Kb = Qb + 1024;
  const short* Vtb = vt + (size_t)bh * 64 * SEQ;

  short8v qf[2][2];
#pragma unroll
  for (int qi = 0; qi < 2; ++qi) {
    const short* qrow = Qb + (size_t)(q0 + wid * 32 + qi * 16 + l15) * RS + kg * 8;
    qf[qi][0] = *(const short8v*)(qrow);
    qf[qi][1] = *(const short8v*)(qrow + 32);
  }

  const int i0 = tid, i1 = tid + 256;
  const int r0 = i0 >> 3, b0 = (i0 & 7) ^ (r0 & 7);
  const int r1 = i1 >> 3, b1 = (i1 & 7) ^ (r1 & 7);
  const short* pk0 = Kb + (size_t)r0 * RS + b0 * 8;
  const short* pk1 = Kb + (size_t)r1 * RS + b1 * 8;
  const short* pv0 = Vtb + (size_t)r0 * SEQ + b0 * 8;
  const short* pv1 = Vtb + (size_t)r1 * SEQ + b1 * 8;

  auto stage = [&](int buf, int kv0) {
    async_copy16(pk0 + (size_t)kv0 * RS, &Ks[buf][i0 * 8]);
    async_copy16(pk1 + (size_t)kv0 * RS, &Ks[buf][i1 * 8]);
    async_copy16(pv0 + kv0, &Vs[buf][i0 * 8]);
    async_copy16(pv1 + kv0, &Vs[buf][i1 * 8]);
  };

  f32x4 o[2][4];
  f32x4 lacc[2];
#pragma unroll
  for (int qi = 0; qi < 2; ++qi) {
    lacc[qi] = (f32x4){0.f, 0.f, 0.f, 0.f};
#pragma unroll
    for (int i = 0; i < 4; ++i) o[qi][i] = (f32x4){0.f, 0.f, 0.f, 0.f};
  }

  const short ONE = 0x3F80;
  const short8v ones = {ONE, ONE, ONE, ONE, ONE, ONE, ONE, ONE};

  const int colblk = ((kg & 1) << 1) | (kg >> 1);

  auto tilebody = [&](auto BUFC, int kv_next, bool do_stage) {
    constexpr int buf = decltype(BUFC)::value;
    if (do_stage) stage(buf ^ 1, kv_next);

    f32x4 s[2][4];
    __builtin_amdgcn_s_setprio(1);
#pragma unroll
    for (int nt = 0; nt < 4; ++nt) {
      const int r = l15 + nt * 16, rx = r & 7;
      const short8v k0 = *(const short8v*)&Ks[buf][r * 64 + ((kg ^ rx) << 3)];
      const short8v k1 = *(const short8v*)&Ks[buf][r * 64 + (((kg + 4) ^ rx) << 3)];
#pragma unroll
      for (int qi = 0; qi < 2; ++qi) {
        f32x4 c = (f32x4){0.f, 0.f, 0.f, 0.f};
        c = __builtin_amdgcn_mfma_f32_16x16x32_bf16(k0, qf[qi][0], c, 0, 0, 0);
        c = __builtin_amdgcn_mfma_f32_16x16x32_bf16(k1, qf[qi][1], c, 0, 0, 0);
        s[qi][nt] = c;
      }
    }
    __builtin_amdgcn_s_setprio(0);

    unsigned w[2][4][2];
#pragma unroll
    for (int qi = 0; qi < 2; ++qi)
#pragma unroll
      for (int nt = 0; nt < 4; ++nt) {
        float p0 = __builtin_amdgcn_exp2f(s[qi][nt][0]);
        float p1 = __builtin_amdgcn_exp2f(s[qi][nt][1]);
        float p2 = __builtin_amdgcn_exp2f(s[qi][nt][2]);
        float p3 = __builtin_amdgcn_exp2f(s[qi][nt][3]);
        w[qi][nt][0] = cvtpk(p0, p1);
        w[qi][nt][1] = cvtpk(p2, p3);
      }

    __builtin_amdgcn_s_setprio(1);
#pragma unroll
    for (int kt = 0; kt < 2; ++kt) {
      short8v pf[2];
#pragma unroll
      for (int qi = 0; qi < 2; ++qi) {
        unsigned x0 = w[qi][2 * kt][0], y0 = w[qi][2 * kt + 1][0];
        unsigned x1 = w[qi][2 * kt][1], y1 = w[qi][2 * kt + 1][1];
        perm16swap(x0, y0);
        perm16swap(x1, y1);
        uint4v uv = {x0, x1, y0, y1};
        pf[qi] = __builtin_bit_cast(short8v, uv);
        lacc[qi] = __builtin_amdgcn_mfma_f32_16x16x32_bf16(ones, pf[qi], lacc[qi], 0, 0, 0);
      }
#pragma unroll
      for (int nt = 0; nt < 4; ++nt) {
        const int r = l15 + nt * 16;
        const short8v vf = *(const short8v*)&Vs[buf][r * 64 + (((colblk + 4 * kt) ^ (r & 7)) << 3)];
#pragma unroll
        for (int qi = 0; qi < 2; ++qi)
          o[qi][nt] = __builtin_amdgcn_mfma_f32_16x16x32_bf16(vf, pf[qi], o[qi][nt], 0, 0, 0);
      }
    }
    __builtin_amdgcn_s_setprio(0);

    __syncthreads();
  };

  stage(0, kvbase);
  __syncthreads();
  for (int kv0 = kvbase; kv0 < kvbase + SEQ / 2; kv0 += 128) {
    tilebody(std::integral_constant<int, 0>{}, kv0 + 64, true);
    tilebody(std::integral_constant<int, 1>{}, kv0 + 128, kv0 + 128 < kvbase + SEQ / 2);
  }

  // partial O^T (f32, NO normalization) and partial l
  float* pob = po + (size_t)half * NROWS * D_MODEL;
#pragma unroll
  for (int qi = 0; qi < 2; ++qi) {
    const int qg = q0 + wid * 32 + qi * 16 + l15;
    float* orow = pob + ((size_t)b * SEQ + qg) * D_MODEL + h * 64;
#pragma unroll
    for (int nt = 0; nt < 4; ++nt)
      *(f32x4*)(orow + nt * 16 + kg * 4) = o[qi][nt];
    if (kg == 0)
      lp[(size_t)half * 65536 + (size_t)bh * SEQ + qg] = lacc[qi][0];
  }
}

// combine: ao = bf16( (po0+po1) / (l0+l1) ).  One block per token row.
__global__ __launch_bounds__(256)
void attn_combine_kernel(const float* __restrict__ po, const float* __restrict__ lp,
                         short* __restrict__ ao) {
  const int row = blockIdx.x;          // b*SEQ + s
  const int b = row >> 11, s5 = row & (SEQ - 1);
  const int t = threadIdx.x;
  const int h = t >> 4;                // 16 threads per head (64 d / 4)
  const float l0 = lp[(size_t)(b * 16 + h) * SEQ + s5];
  const float l1 = lp[65536 + (size_t)(b * 16 + h) * SEQ + s5];
  const float linv = 1.0f / (l0 + l1);
  const size_t base = (size_t)row * D_MODEL + t * 4;
  const f32x4 a0 = *(const f32x4*)(po + base);
  const f32x4 a1 = *(const f32x4*)(po + (size_t)NROWS * D_MODEL + base);
  short4 st;
  st.x = f2bs((a0[0] + a1[0]) * linv);
  st.y = f2bs((a0[1] + a1[1]) * linv);
  st.z = f2bs((a0[2] + a1[2]) * linv);
  st.w = f2bs((a0[3] + a1[3]) * linv);
  *(short4*)(ao + base) = st;
}

// ---------------- workspace layout ----------
static constexpr size_t OFF_WQKV = 0;          // 3072x1024 bf16
static constexpr size_t OFF_WO   = 6291456;    // 1024x1024 bf16
static constexpr size_t OFF_W1   = 8388608;    // 4096x1024 bf16
static constexpr size_t OFF_W2   = 16777216;   // 1024x4096 bf16
static constexpr size_t OFF_BQKV = 25165824;   // 3072 f32
static constexpr size_t OFF_H1   = 25178112;   // 4096x1024 bf16 (reused for V^T)
static constexpr size_t OFF_QKV  = 33566720;   // 4096x3072 bf16
static constexpr size_t OFF_AO   = 58732544;   // 4096x1024 bf16
static constexpr size_t OFF_H2   = 67121152;   // 4096x1024 bf16 (lp borrows this
                                               //  region pre-LN2: 512KB)
static constexpr size_t OFF_F1   = 75509760;   // 4096x4096 bf16 (po borrows this
                                               //  region pre-FFN1: 2x16.78MB)
static constexpr size_t OFF_VT   = OFF_H1;     // 32x64x2048 bf16 = 8 MB

extern "C" void kernel_launch(void* const* d_in, const int* in_sizes, int n_in,
                              void* d_out, int out_size, void* d_ws, size_t ws_size,
                              hipStream_t stream) {
  const float* x  = (const float*)d_in[0];
  const float* wq = (const float*)d_in[2];
  const float* bq = (const float*)d_in[3];
  const float* wk = (const float*)d_in[4];
  const float* bk = (const float*)d_in[5];
  const float* wv = (const float*)d_in[6];
  const float* bv = (const float*)d_in[7];
  const float* wo = (const float*)d_in[8];
  const float* bo = (const float*)d_in[9];
  const float* w1 = (const float*)d_in[10];
  const float* b1 = (const float*)d_in[11];
  const float* w2 = (const float*)d_in[12];
  const float* b2 = (const float*)d_in[13];
  const float* a1 = (const float*)d_in[14];
  const float* c1 = (const float*)d_in[15];
  const float* a2 = (const float*)d_in[16];
  const float* c2 = (const float*)d_in[17];
  float* outp = (float*)d_out;
  char* ws = (char*)d_ws;

  short* wqkv_t = (short*)(ws + OFF_WQKV);
  short* wo_t   = (short*)(ws + OFF_WO);
  short* w1_t   = (short*)(ws + OFF_W1);
  short* w2_t   = (short*)(ws + OFF_W2);
  float* bqkv   = (float*)(ws + OFF_BQKV);
  short* h1     = (short*)(ws + OFF_H1);
  short* qkv    = (short*)(ws + OFF_QKV);
  short* ao     = (short*)(ws + OFF_AO);
  short* h2     = (short*)(ws + OFF_H2);
  short* f1     = (short*)(ws + OFF_F1);
  short* vtb    = (short*)(ws + OFF_VT);
  float* po     = (float*)(ws + OFF_F1);   // 2 x 16.78MB partial O^T (pre-FFN1)
  float* lp     = (float*)(ws + OFF_H2);   // 2 x 256KB partial l (pre-LN2)

  const float QSCALE = 0.125f * 1.44269504f;  // 1/sqrt(64) * log2(e)
  const dim3 tb(32, 8);
  transpose4_bf16_kernel<<<dim3(32, 32, 4), tb, 0, stream>>>(
      wq, wk, wv, wo, wqkv_t, wo_t, QSCALE);
  transpose_ffn_kernel<<<dim3(128, 32, 2), tb, 0, stream>>>(w1, w2, w1_t, w2_t);
  concat_bias_kernel<<<12, 256, 0, stream>>>(bq, bk, bv, bqkv, QSCALE);

  // LN1 -> fused QKV GEMM -> V^T transpose -> attention (kv-split) -> combine
  // -> Wo GEMM (+resid x, fp32 into d_out)
  layernorm_kernel<<<NROWS, 256, 0, stream>>>(x, h1, a1, c1);
  gemm_bt_sb_kernel<4, 4, false, false, true><<<dim3(24, 32), 256, 0, stream>>>(
      h1, wqkv_t, bqkv, nullptr, qkv, NROWS, 3072, 1024);
  transpose_v_kernel<<<dim3(64, 2, 32), 256, 0, stream>>>(qkv, vtb);
  attn_kernel<<<dim3(16, 32, 2), 256, 0, stream>>>(qkv, vtb, po, lp);
  attn_combine_kernel<<<NROWS, 256, 0, stream>>>(po, lp, ao);
  gemm_bt_k64_kernel<false, true, false><<<dim3(16, 64), 256, 0, stream>>>(
      ao, wo_t, bo, x, d_out, NROWS, 1024, 1024);

  // LN2 -> FFN1 (+ReLU) -> FFN2 (+resid, in-place on d_out)
  layernorm_kernel<<<NROWS, 256, 0, stream>>>(outp, h2, a2, c2);
  gemm_bt_sb_kernel<4, 4, true, false, true><<<dim3(32, 32), 256, 0, stream>>>(
      h2, w1_t, b1, nullptr, f1, NROWS, 4096, 1024);
  gemm_bt_k64_kernel<false, true, false><<<dim3(16, 64), 256, 0, stream>>>(
      f1, w2_t, b2, outp, d_out, NROWS, 1024, 4096);
}

// Round 21
// 224.943 us; speedup vs baseline: 1.0601x; 1.0601x over previous
//
#include <hip/hip_runtime.h>
#include <hip/hip_bf16.h>
#include <type_traits>

// EncoderBlock on MI355X — bf16 MFMA everywhere.
// R21: exact revert to R18 (best measured: 225.4us). R19 (T4 attn) and R20
// (kv-split attn) both regressed — attn occupancy is chain-limited, not
// grid/drain-limited. All components now at measured structural limits of
// their kernel families (see session ledger).

typedef __attribute__((ext_vector_type(8))) short short8v;
typedef __attribute__((ext_vector_type(4))) float f32x4;
typedef __attribute__((ext_vector_type(4))) unsigned uint4v;

#define D_MODEL 1024
#define SEQ 2048
#define NROWS 4096   // B*S

__device__ __forceinline__ short f2bs(float f) {
  __hip_bfloat16 h = __float2bfloat16(f);
  return __builtin_bit_cast(short, h);
}

__device__ __forceinline__ unsigned cvtpk(float lo, float hi) {
  unsigned r;
  asm("v_cvt_pk_bf16_f32 %0, %1, %2" : "=v"(r) : "v"(lo), "v"(hi));
  return r;
}

__device__ __forceinline__ void perm16swap(unsigned& a, unsigned& b) {
  asm volatile("v_permlane16_swap_b32 %0, %1" : "+v"(a), "+v"(b));
}

__device__ __forceinline__ void async_copy16(const void* g, void* l) {
  __builtin_amdgcn_global_load_lds(
      (__attribute__((address_space(1))) void*)g,
      (__attribute__((address_space(3))) void*)l,
      16, 0, 0);
}

// ---------------- weight transpose + fp32->bf16 convert (+scale) -------------
__global__ __launch_bounds__(256)
void transpose4_bf16_kernel(const float* __restrict__ wq, const float* __restrict__ wk,
                            const float* __restrict__ wv, const float* __restrict__ wo,
                            short* __restrict__ oq, short* __restrict__ ow,
                            float qscale) {
  __shared__ float tile[32][33];
  const int z = blockIdx.z;
  const float* in = (z == 0) ? wq : (z == 1) ? wk : (z == 2) ? wv : wo;
  short* out = (z < 3) ? (oq + (size_t)z * 1024 * 1024) : ow;
  const float scale = (z == 0) ? qscale : 1.0f;
  const int n0 = blockIdx.x * 32, k0 = blockIdx.y * 32;
  const int tx = threadIdx.x, ty = threadIdx.y;  // (32,8)
#pragma unroll
  for (int j = 0; j < 4; ++j)
    tile[ty + j * 8][tx] = in[(size_t)(k0 + ty + j * 8) * 1024 + n0 + tx];
  __syncthreads();
#pragma unroll
  for (int j = 0; j < 4; ++j)
    out[(size_t)(n0 + ty + j * 8) * 1024 + k0 + tx] = f2bs(tile[tx][ty + j * 8] * scale);
}

// w1 (1024x4096) and w2 (4096x1024) in one launch (z swaps grid roles).
__global__ __launch_bounds__(256)
void transpose_ffn_kernel(const float* __restrict__ w1, const float* __restrict__ w2,
                          short* __restrict__ o1, short* __restrict__ o2) {
  __shared__ float tile[32][33];
  const int z = blockIdx.z;
  const float* in = z ? w2 : w1;
  short* out = z ? o2 : o1;
  const int K = z ? 4096 : 1024, N = z ? 1024 : 4096;
  const int n0 = (z ? blockIdx.y : blockIdx.x) * 32;
  const int k0 = (z ? blockIdx.x : blockIdx.y) * 32;
  const int tx = threadIdx.x, ty = threadIdx.y;  // (32,8)
#pragma unroll
  for (int j = 0; j < 4; ++j)
    tile[ty + j * 8][tx] = in[(size_t)(k0 + ty + j * 8) * N + n0 + tx];
  __syncthreads();
#pragma unroll
  for (int j = 0; j < 4; ++j)
    out[(size_t)(n0 + ty + j * 8) * K + k0 + tx] = f2bs(tile[tx][ty + j * 8]);
}

// v-part of qkv (token, 2048 + h*64 + d) -> vt[(b*16+h)*64 + d][kv=s]
__global__ __launch_bounds__(256)
void transpose_v_kernel(const short* __restrict__ qkv, short* __restrict__ vt) {
  __shared__ short tile[32][36];     // +4 pad: col-reads 2-way (free)
  const int bh = blockIdx.z, b = bh >> 4, h = bh & 15;
  const int s0 = blockIdx.x * 32, d0 = blockIdx.y * 32;
  const int tid = threadIdx.x;
  const short* src = qkv + ((size_t)b * SEQ) * 3072 + 2048 + h * 64;
  const int row = tid >> 3, c4 = (tid & 7) * 4;
  *(short4*)&tile[row][c4] = *(const short4*)&src[(size_t)(s0 + row) * 3072 + d0 + c4];
  __syncthreads();
  short* dst = vt + (size_t)bh * 64 * SEQ;
  const int dr = tid >> 5, sc = tid & 31;
#pragma unroll
  for (int j = 0; j < 4; ++j)
    dst[(size_t)(d0 + dr + j * 8) * SEQ + s0 + sc] = tile[sc][dr + j * 8];
}

__global__ void concat_bias_kernel(const float* __restrict__ bq, const float* __restrict__ bk,
                                   const float* __restrict__ bv, float* __restrict__ outb,
                                   float qscale) {
  int i = blockIdx.x * 256 + threadIdx.x;  // 3072 total
  float v = (i < 1024) ? bq[i] * qscale : (i < 2048 ? bk[i - 1024] : bv[i - 2048]);
  outb[i] = v;
}

// ---------------- LayerNorm (torch semantics: ddof=1, eps on std) -> bf16 ----
__global__ __launch_bounds__(256)
void layernorm_kernel(const float* __restrict__ x, short* __restrict__ out,
                      const float* __restrict__ alpha, const float* __restrict__ beta) {
  const int row = blockIdx.x;
  const int t = threadIdx.x;
  float4 v = ((const float4*)(x + (size_t)row * D_MODEL))[t];
  float s = v.x + v.y + v.z + v.w;
  float sq = v.x * v.x + v.y * v.y + v.z * v.z + v.w * v.w;
#pragma unroll
  for (int m = 1; m < 64; m <<= 1) {
    s += __shfl_xor(s, m, 64);
    sq += __shfl_xor(sq, m, 64);
  }
  __shared__ float sh_s[4], sh_q[4];
  const int wid = t >> 6;
  if ((t & 63) == 0) { sh_s[wid] = s; sh_q[wid] = sq; }
  __syncthreads();
  s = sh_s[0] + sh_s[1] + sh_s[2] + sh_s[3];
  sq = sh_q[0] + sh_q[1] + sh_q[2] + sh_q[3];
  const float mean = s * (1.0f / 1024.0f);
  const float var = fmaxf(0.0f, (sq - 1024.0f * mean * mean) * (1.0f / 1023.0f));
  const float scl = alpha[0] / (sqrtf(var) + 1e-6f);
  const float sft = beta[0];
  short4 o;
  o.x = f2bs((v.x - mean) * scl + sft);
  o.y = f2bs((v.y - mean) * scl + sft);
  o.z = f2bs((v.z - mean) * scl + sft);
  o.w = f2bs((v.w - mean) * scl + sft);
  ((short4*)(out + (size_t)row * D_MODEL))[t] = o;
}

// ---------------- big GEMM: 128x128, BK=64, single-buffer, full swizzle ------
template <int MF, int NF, bool RELU, bool RESID, bool OUT_BF16>
__global__ __launch_bounds__(256)
void gemm_bt_sb_kernel(const short* __restrict__ A, const short* __restrict__ Bt,
                       const float* __restrict__ bias, const float* __restrict__ resid,
                       void* __restrict__ out, int M, int N, int K) {
  constexpr int BM = MF * 32, BN = NF * 32, BK = 64;
  __shared__ short As[BM * BK];
  __shared__ short Bs[BN * BK];
  const int tid = threadIdx.x;
  const int lane = tid & 63, wid = tid >> 6;
  const int wr = wid >> 1, wc = wid & 1;
  const int l15 = lane & 15, kg = lane >> 4;

  const int gx = gridDim.x;
  const int nwg = gx * gridDim.y;
  const int bid = blockIdx.y * gx + blockIdx.x;
  const int tilei = (bid & 7) * (nwg >> 3) + (bid >> 3);
  const int m0 = (tilei / gx) * BM, n0 = (tilei % gx) * BN;

  f32x4 acc[MF][NF];
#pragma unroll
  for (int m = 0; m < MF; ++m)
#pragma unroll
    for (int n = 0; n < NF; ++n) acc[m][n] = (f32x4){0.f, 0.f, 0.f, 0.f};

  const int r0 = tid >> 3, c0 = tid & 7;
  const int csw = (c0 ^ (r0 & 7)) << 3;
  const short* pa = A + (size_t)(m0 + r0) * K + csw;
  const short* pb = Bt + (size_t)(n0 + r0) * K + csw;

  const int NT = K / BK;
  for (int t = 0; t < NT; ++t) {
    const size_t ko = (size_t)t * BK;
#pragma unroll
    for (int it = 0; it < MF; ++it)
      async_copy16(pa + (size_t)it * 32 * K + ko, &As[(tid + it * 256) * 8]);
#pragma unroll
    for (int it = 0; it < NF; ++it)
      async_copy16(pb + (size_t)it * 32 * K + ko, &Bs[(tid + it * 256) * 8]);
    __syncthreads();

    short8v a[2][MF], b[2][NF];
#pragma unroll
    for (int m = 0; m < MF; ++m) {
      const int row = wr * MF * 16 + m * 16 + l15;
#pragma unroll
      for (int kt = 0; kt < 2; ++kt)
        a[kt][m] = *(const short8v*)&As[row * BK + (((kg + 4 * kt) ^ (row & 7)) << 3)];
    }
#pragma unroll
    for (int n = 0; n < NF; ++n) {
      const int row = wc * NF * 16 + n * 16 + l15;
#pragma unroll
      for (int kt = 0; kt < 2; ++kt)
        b[kt][n] = *(const short8v*)&Bs[row * BK + (((kg + 4 * kt) ^ (row & 7)) << 3)];
    }
    __builtin_amdgcn_s_setprio(1);
#pragma unroll
    for (int kt = 0; kt < 2; ++kt)
#pragma unroll
      for (int m = 0; m < MF; ++m)
#pragma unroll
        for (int n = 0; n < NF; ++n)
          acc[m][n] = __builtin_amdgcn_mfma_f32_16x16x32_bf16(a[kt][m], b[kt][n], acc[m][n], 0, 0, 0);
    __builtin_amdgcn_s_setprio(0);
    __syncthreads();
  }

#pragma unroll
  for (int m = 0; m < MF; ++m) {
#pragma unroll
    for (int n = 0; n < NF; ++n) {
      const int col = n0 + wc * NF * 16 + n * 16 + l15;
      const float bv = bias[col];
#pragma unroll
      for (int r = 0; r < 4; ++r) {
        const size_t row = (size_t)(m0 + wr * MF * 16 + m * 16 + kg * 4 + r);
        float v = acc[m][n][r] + bv;
        if (RELU) v = fmaxf(v, 0.0f);
        if (RESID) v += resid[row * N + col];
        if (OUT_BF16)
          ((short*)out)[row * N + col] = f2bs(v);
        else
          ((float*)out)[row * N + col] = v;
      }
    }
  }
}

// ---------------- skinny GEMM: 64x64, BK=64, dbuf, hoisted staging (R15) -----
template <bool RELU, bool RESID, bool OUT_BF16>
__global__ __launch_bounds__(256)
void gemm_bt_k64_kernel(const short* __restrict__ A, const short* __restrict__ Bt,
                        const float* __restrict__ bias, const float* __restrict__ resid,
                        void* __restrict__ out, int M, int N, int K) {
  constexpr int BM = 64, BN = 64, BK = 64;
  __shared__ short As[2][BM * BK];
  __shared__ short Bs[2][BN * BK];
  const int tid = threadIdx.x;
  const int lane = tid & 63, wid = tid >> 6;
  const int wr = wid >> 1, wc = wid & 1;
  const int l15 = lane & 15, kg = lane >> 4;

  const int gx = gridDim.x;
  const int nwg = gx * gridDim.y;
  const int bid = blockIdx.y * gx + blockIdx.x;
  const int tilei = (bid & 7) * (nwg >> 3) + (bid >> 3);
  const int m0 = (tilei / gx) * BM, n0 = (tilei % gx) * BN;

  f32x4 acc[2][2];
#pragma unroll
  for (int m = 0; m < 2; ++m)
#pragma unroll
    for (int n = 0; n < 2; ++n) acc[m][n] = (f32x4){0.f, 0.f, 0.f, 0.f};

  // hoisted staging pointers: chunks {tid, tid+256} for A and for B
  const int rA0 = tid >> 3, cA0 = (((tid & 7)) ^ (rA0 & 7)) << 3;
  const int rA1 = (tid + 256) >> 3, cA1 = (((tid + 256) & 7) ^ (rA1 & 7)) << 3;
  const short* pa0 = A + (size_t)(m0 + rA0) * K + cA0;
  const short* pa1 = A + (size_t)(m0 + rA1) * K + cA1;
  const short* pb0 = Bt + (size_t)(n0 + rA0) * K + cA0;
  const short* pb1 = Bt + (size_t)(n0 + rA1) * K + cA1;

  auto stage = [&](int buf, int t) {
    const size_t ko = (size_t)t * BK;
    async_copy16(pa0 + ko, &As[buf][tid * 8]);
    async_copy16(pa1 + ko, &As[buf][(tid + 256) * 8]);
    async_copy16(pb0 + ko, &Bs[buf][tid * 8]);
    async_copy16(pb1 + ko, &Bs[buf][(tid + 256) * 8]);
  };

  const int NT = K / BK;

  auto bodyk = [&](auto BUFC, int t) {
    constexpr int buf = decltype(BUFC)::value;
    if (t + 1 < NT) stage(buf ^ 1, t + 1);
    short8v a[2][2], b[2][2];
#pragma unroll
    for (int m = 0; m < 2; ++m) {
      const int row = wr * 32 + m * 16 + l15;
#pragma unroll
      for (int kt = 0; kt < 2; ++kt)
        a[kt][m] = *(const short8v*)&As[buf][row * BK + (((kg + 4 * kt) ^ (row & 7)) << 3)];
    }
#pragma unroll
    for (int n = 0; n < 2; ++n) {
      const int row = wc * 32 + n * 16 + l15;
#pragma unroll
      for (int kt = 0; kt < 2; ++kt)
        b[kt][n] = *(const short8v*)&Bs[buf][row * BK + (((kg + 4 * kt) ^ (row & 7)) << 3)];
    }
    __builtin_amdgcn_s_setprio(1);
#pragma unroll
    for (int kt = 0; kt < 2; ++kt)
#pragma unroll
      for (int m = 0; m < 2; ++m)
#pragma unroll
        for (int n = 0; n < 2; ++n)
          acc[m][n] = __builtin_amdgcn_mfma_f32_16x16x32_bf16(a[kt][m], b[kt][n], acc[m][n], 0, 0, 0);
    __builtin_amdgcn_s_setprio(0);
    __syncthreads();   // drains vmcnt(0): next buf staged; this buf reusable
  };

  stage(0, 0);
  __syncthreads();
  for (int t = 0; t < NT; t += 2) {   // NT = 16 or 64: always even
    bodyk(std::integral_constant<int, 0>{}, t);
    bodyk(std::integral_constant<int, 1>{}, t + 1);
  }

#pragma unroll
  for (int m = 0; m < 2; ++m) {
#pragma unroll
    for (int n = 0; n < 2; ++n) {
      const int col = n0 + wc * 32 + n * 16 + l15;
      const float bv = bias[col];
#pragma unroll
      for (int r = 0; r < 4; ++r) {
        const size_t row = (size_t)(m0 + wr * 32 + m * 16 + kg * 4 + r);
        float v = acc[m][n][r] + bv;
        if (RELU) v = fmaxf(v, 0.0f);
        if (RESID) v += resid[row * N + col];
        if (OUT_BF16)
          ((short*)out)[row * N + col] = f2bs(v);
        else
          ((float*)out)[row * N + col] = v;
      }
    }
  }
}

// ---------------- Flash attention: QBLK=128 (32 q/wave, 2 Q-frags) -----------
__global__ __launch_bounds__(256)
void attn_kernel(const short* __restrict__ qkv, const short* __restrict__ vt,
                 short* __restrict__ out) {
  const int bh = blockIdx.y;        // b*16+h
  const int b = bh >> 4, h = bh & 15;
  const int q0 = blockIdx.x * 128;
  const int tid = threadIdx.x;
  const int lane = tid & 63, wid = tid >> 6;
  const int l15 = lane & 15, kg = lane >> 4;

  __shared__ short Ks[2][64 * 64];
  __shared__ short Vs[2][64 * 64];

  const size_t RS = 3072;
  const short* Qb = qkv + (size_t)b * SEQ * RS + h * 64;
  const short* Kb = Qb + 1024;
  const short* Vtb = vt + (size_t)bh * 64 * SEQ;

  short8v qf[2][2];
#pragma unroll
  for (int qi = 0; qi < 2; ++qi) {
    const short* qrow = Qb + (size_t)(q0 + wid * 32 + qi * 16 + l15) * RS + kg * 8;
    qf[qi][0] = *(const short8v*)(qrow);
    qf[qi][1] = *(const short8v*)(qrow + 32);
  }

  const int i0 = tid, i1 = tid + 256;
  const int r0 = i0 >> 3, b0 = (i0 & 7) ^ (r0 & 7);
  const int r1 = i1 >> 3, b1 = (i1 & 7) ^ (r1 & 7);
  const short* pk0 = Kb + (size_t)r0 * RS + b0 * 8;
  const short* pk1 = Kb + (size_t)r1 * RS + b1 * 8;
  const short* pv0 = Vtb + (size_t)r0 * SEQ + b0 * 8;
  const short* pv1 = Vtb + (size_t)r1 * SEQ + b1 * 8;

  auto stage = [&](int buf, int kv0) {
    async_copy16(pk0 + (size_t)kv0 * RS, &Ks[buf][i0 * 8]);
    async_copy16(pk1 + (size_t)kv0 * RS, &Ks[buf][i1 * 8]);
    async_copy16(pv0 + kv0, &Vs[buf][i0 * 8]);
    async_copy16(pv1 + kv0, &Vs[buf][i1 * 8]);
  };

  f32x4 o[2][4];
  f32x4 lacc[2];
#pragma unroll
  for (int qi = 0; qi < 2; ++qi) {
    lacc[qi] = (f32x4){0.f, 0.f, 0.f, 0.f};
#pragma unroll
    for (int i = 0; i < 4; ++i) o[qi][i] = (f32x4){0.f, 0.f, 0.f, 0.f};
  }

  const short ONE = 0x3F80;
  const short8v ones = {ONE, ONE, ONE, ONE, ONE, ONE, ONE, ONE};

  const int colblk = ((kg & 1) << 1) | (kg >> 1);

  auto tilebody = [&](auto BUFC, int kv_next, bool do_stage) {
    constexpr int buf = decltype(BUFC)::value;
    if (do_stage) stage(buf ^ 1, kv_next);

    f32x4 s[2][4];
    __builtin_amdgcn_s_setprio(1);
#pragma unroll
    for (int nt = 0; nt < 4; ++nt) {
      const int r = l15 + nt * 16, rx = r & 7;
      const short8v k0 = *(const short8v*)&Ks[buf][r * 64 + ((kg ^ rx) << 3)];
      const short8v k1 = *(const short8v*)&Ks[buf][r * 64 + (((kg + 4) ^ rx) << 3)];
#pragma unroll
      for (int qi = 0; qi < 2; ++qi) {
        f32x4 c = (f32x4){0.f, 0.f, 0.f, 0.f};
        c = __builtin_amdgcn_mfma_f32_16x16x32_bf16(k0, qf[qi][0], c, 0, 0, 0);
        c = __builtin_amdgcn_mfma_f32_16x16x32_bf16(k1, qf[qi][1], c, 0, 0, 0);
        s[qi][nt] = c;
      }
    }
    __builtin_amdgcn_s_setprio(0);

    unsigned w[2][4][2];
#pragma unroll
    for (int qi = 0; qi < 2; ++qi)
#pragma unroll
      for (int nt = 0; nt < 4; ++nt) {
        float p0 = __builtin_amdgcn_exp2f(s[qi][nt][0]);
        float p1 = __builtin_amdgcn_exp2f(s[qi][nt][1]);
        float p2 = __builtin_amdgcn_exp2f(s[qi][nt][2]);
        float p3 = __builtin_amdgcn_exp2f(s[qi][nt][3]);
        w[qi][nt][0] = cvtpk(p0, p1);
        w[qi][nt][1] = cvtpk(p2, p3);
      }

    __builtin_amdgcn_s_setprio(1);
#pragma unroll
    for (int kt = 0; kt < 2; ++kt) {
      short8v pf[2];
#pragma unroll
      for (int qi = 0; qi < 2; ++qi) {
        unsigned x0 = w[qi][2 * kt][0], y0 = w[qi][2 * kt + 1][0];
        unsigned x1 = w[qi][2 * kt][1], y1 = w[qi][2 * kt + 1][1];
        perm16swap(x0, y0);
        perm16swap(x1, y1);
        uint4v uv = {x0, x1, y0, y1};
        pf[qi] = __builtin_bit_cast(short8v, uv);
        lacc[qi] = __builtin_amdgcn_mfma_f32_16x16x32_bf16(ones, pf[qi], lacc[qi], 0, 0, 0);
      }
#pragma unroll
      for (int nt = 0; nt < 4; ++nt) {
        const int r = l15 + nt * 16;
        const short8v vf = *(const short8v*)&Vs[buf][r * 64 + (((colblk + 4 * kt) ^ (r & 7)) << 3)];
#pragma unroll
        for (int qi = 0; qi < 2; ++qi)
          o[qi][nt] = __builtin_amdgcn_mfma_f32_16x16x32_bf16(vf, pf[qi], o[qi][nt], 0, 0, 0);
      }
    }
    __builtin_amdgcn_s_setprio(0);

    __syncthreads();
  };

  stage(0, 0);
  __syncthreads();
  for (int kv0 = 0; kv0 < SEQ; kv0 += 128) {
    tilebody(std::integral_constant<int, 0>{}, kv0 + 64, true);
    tilebody(std::integral_constant<int, 1>{}, kv0 + 128, kv0 + 128 < SEQ);
  }

#pragma unroll
  for (int qi = 0; qi < 2; ++qi) {
    const float linv = 1.0f / lacc[qi][0];
    short* ob = out + ((size_t)b * SEQ + q0 + wid * 32 + qi * 16 + l15) * D_MODEL + h * 64;
#pragma unroll
    for (int nt = 0; nt < 4; ++nt) {
      short4 st;
      st.x = f2bs(o[qi][nt][0] * linv);
      st.y = f2bs(o[qi][nt][1] * linv);
      st.z = f2bs(o[qi][nt][2] * linv);
      st.w = f2bs(o[qi][nt][3] * linv);
      *(short4*)(ob + nt * 16 + kg * 4) = st;
    }
  }
}

// ---------------- workspace layout ----------
static constexpr size_t OFF_WQKV = 0;          // 3072x1024 bf16
static constexpr size_t OFF_WO   = 6291456;    // 1024x1024 bf16
static constexpr size_t OFF_W1   = 8388608;    // 4096x1024 bf16
static constexpr size_t OFF_W2   = 16777216;   // 1024x4096 bf16
static constexpr size_t OFF_BQKV = 25165824;   // 3072 f32
static constexpr size_t OFF_H1   = 25178112;   // 4096x1024 bf16 (reused for V^T)
static constexpr size_t OFF_QKV  = 33566720;   // 4096x3072 bf16
static constexpr size_t OFF_AO   = 58732544;   // 4096x1024 bf16
static constexpr size_t OFF_H2   = 67121152;   // 4096x1024 bf16
static constexpr size_t OFF_F1   = 75509760;   // 4096x4096 bf16
static constexpr size_t OFF_VT   = OFF_H1;     // 32x64x2048 bf16 = 8 MB

extern "C" void kernel_launch(void* const* d_in, const int* in_sizes, int n_in,
                              void* d_out, int out_size, void* d_ws, size_t ws_size,
                              hipStream_t stream) {
  const float* x  = (const float*)d_in[0];
  const float* wq = (const float*)d_in[2];
  const float* bq = (const float*)d_in[3];
  const float* wk = (const float*)d_in[4];
  const float* bk = (const float*)d_in[5];
  const float* wv = (const float*)d_in[6];
  const float* bv = (const float*)d_in[7];
  const float* wo = (const float*)d_in[8];
  const float* bo = (const float*)d_in[9];
  const float* w1 = (const float*)d_in[10];
  const float* b1 = (const float*)d_in[11];
  const float* w2 = (const float*)d_in[12];
  const float* b2 = (const float*)d_in[13];
  const float* a1 = (const float*)d_in[14];
  const float* c1 = (const float*)d_in[15];
  const float* a2 = (const float*)d_in[16];
  const float* c2 = (const float*)d_in[17];
  float* outp = (float*)d_out;
  char* ws = (char*)d_ws;

  short* wqkv_t = (short*)(ws + OFF_WQKV);
  short* wo_t   = (short*)(ws + OFF_WO);
  short* w1_t   = (short*)(ws + OFF_W1);
  short* w2_t   = (short*)(ws + OFF_W2);
  float* bqkv   = (float*)(ws + OFF_BQKV);
  short* h1     = (short*)(ws + OFF_H1);
  short* qkv    = (short*)(ws + OFF_QKV);
  short* ao     = (short*)(ws + OFF_AO);
  short* h2     = (short*)(ws + OFF_H2);
  short* f1     = (short*)(ws + OFF_F1);
  short* vtb    = (short*)(ws + OFF_VT);

  const float QSCALE = 0.125f * 1.44269504f;  // 1/sqrt(64) * log2(e)
  const dim3 tb(32, 8);
  transpose4_bf16_kernel<<<dim3(32, 32, 4), tb, 0, stream>>>(
      wq, wk, wv, wo, wqkv_t, wo_t, QSCALE);
  transpose_ffn_kernel<<<dim3(128, 32, 2), tb, 0, stream>>>(w1, w2, w1_t, w2_t);
  concat_bias_kernel<<<12, 256, 0, stream>>>(bq, bk, bv, bqkv, QSCALE);

  // LN1 -> fused QKV GEMM -> V^T transpose -> attention -> Wo GEMM (+resid x)
  layernorm_kernel<<<NROWS, 256, 0, stream>>>(x, h1, a1, c1);
  gemm_bt_sb_kernel<4, 4, false, false, true><<<dim3(24, 32), 256, 0, stream>>>(
      h1, wqkv_t, bqkv, nullptr, qkv, NROWS, 3072, 1024);
  transpose_v_kernel<<<dim3(64, 2, 32), 256, 0, stream>>>(qkv, vtb);
  attn_kernel<<<dim3(16, 32), 256, 0, stream>>>(qkv, vtb, ao);
  gemm_bt_k64_kernel<false, true, false><<<dim3(16, 64), 256, 0, stream>>>(
      ao, wo_t, bo, x, d_out, NROWS, 1024, 1024);

  // LN2 -> FFN1 (+ReLU) -> FFN2 (+resid, in-place on d_out)
  layernorm_kernel<<<NROWS, 256, 0, stream>>>(outp, h2, a2, c2);
  gemm_bt_sb_kernel<4, 4, true, false, true><<<dim3(32, 32), 256, 0, stream>>>(
      h2, w1_t, b1, nullptr, f1, NROWS, 4096, 1024);
  gemm_bt_k64_kernel<false, true, false><<<dim3(16, 64), 256, 0, stream>>>(
      f1, w2_t, b2, outp, d_out, NROWS, 1024, 4096);
}